// Round 1
// baseline (5497.630 us; speedup 1.0000x reference)
//
#include <hip/hip_runtime.h>

#define N_EDGES 3200000
#define N_NODES 100000

__global__ void mpn_kernel(
    const float* __restrict__ x_node,
    const float* __restrict__ x_edge,
    const int* __restrict__ src,
    const int* __restrict__ dst,
    const float* __restrict__ We1, const float* __restrict__ be1,
    const float* __restrict__ We2, const float* __restrict__ be2,
    const float* __restrict__ Wn1, const float* __restrict__ bn1,
    const float* __restrict__ Wn2, const float* __restrict__ bn2,
    float* __restrict__ nm_out,   // [N_NODES, 32]
    float* __restrict__ em_out)   // [N_EDGES, 6]
{
    const int e = blockIdx.x * 256 + threadIdx.x;
    const int d = dst[e];
    const int s = src[e];

    // Gather endpoint node features (128B rows, float4 loads; L2/L3 resident)
    float xd[32], xs[32];
    {
        const float4* pd = (const float4*)(x_node + (size_t)d * 32);
        const float4* ps = (const float4*)(x_node + (size_t)s * 32);
        #pragma unroll
        for (int i = 0; i < 8; ++i) {
            float4 v = pd[i];
            xd[4*i+0] = v.x; xd[4*i+1] = v.y; xd[4*i+2] = v.z; xd[4*i+3] = v.w;
        }
        #pragma unroll
        for (int i = 0; i < 8; ++i) {
            float4 v = ps[i];
            xs[4*i+0] = v.x; xs[4*i+1] = v.y; xs[4*i+2] = v.z; xs[4*i+3] = v.w;
        }
    }
    float xe[6];
    {
        const float2* pe = (const float2*)(x_edge + (size_t)e * 6);
        float2 a = pe[0], b = pe[1], c = pe[2];
        xe[0]=a.x; xe[1]=a.y; xe[2]=b.x; xe[3]=b.y; xe[4]=c.x; xe[5]=c.y;
    }

    // ---- edge MLP layer 1: h1 = relu([xd,xs,xe] @ We1 + be1), We1 is [70][32]
    float h1[32];
    #pragma unroll
    for (int j = 0; j < 32; ++j) h1[j] = be1[j];
    for (int k = 0; k < 32; ++k) {
        const float a = xd[k];
        const float* w = We1 + k * 32;
        #pragma unroll
        for (int j = 0; j < 32; ++j) h1[j] = fmaf(a, w[j], h1[j]);
    }
    for (int k = 0; k < 32; ++k) {
        const float a = xs[k];
        const float* w = We1 + (32 + k) * 32;
        #pragma unroll
        for (int j = 0; j < 32; ++j) h1[j] = fmaf(a, w[j], h1[j]);
    }
    #pragma unroll
    for (int k = 0; k < 6; ++k) {
        const float a = xe[k];
        const float* w = We1 + (64 + k) * 32;
        #pragma unroll
        for (int j = 0; j < 32; ++j) h1[j] = fmaf(a, w[j], h1[j]);
    }
    #pragma unroll
    for (int j = 0; j < 32; ++j) h1[j] = fmaxf(h1[j], 0.0f);

    // ---- edge MLP layer 2: em = relu(h1 @ We2 + be2), We2 is [32][6]
    float em[6];
    #pragma unroll
    for (int j = 0; j < 6; ++j) em[j] = be2[j];
    for (int k = 0; k < 32; ++k) {
        const float a = h1[k];
        const float* w = We2 + k * 6;
        #pragma unroll
        for (int j = 0; j < 6; ++j) em[j] = fmaf(a, w[j], em[j]);
    }
    #pragma unroll
    for (int j = 0; j < 6; ++j) em[j] = fmaxf(em[j], 0.0f);

    // write edge_msg [E,6] (second output), coalesced-ish 24B/thread
    {
        float2* eo = (float2*)(em_out + (size_t)e * 6);
        eo[0] = make_float2(em[0], em[1]);
        eo[1] = make_float2(em[2], em[3]);
        eo[2] = make_float2(em[4], em[5]);
    }

    // ---- node MLP layer 1: h2 = relu([xd, em] @ Wn1 + bn1), Wn1 is [38][64]
    float h2[64];
    #pragma unroll
    for (int j = 0; j < 64; ++j) h2[j] = bn1[j];
    for (int k = 0; k < 32; ++k) {
        const float a = xd[k];
        const float* w = Wn1 + k * 64;
        #pragma unroll
        for (int j = 0; j < 64; ++j) h2[j] = fmaf(a, w[j], h2[j]);
    }
    #pragma unroll
    for (int k = 0; k < 6; ++k) {
        const float a = em[k];
        const float* w = Wn1 + (32 + k) * 64;
        #pragma unroll
        for (int j = 0; j < 64; ++j) h2[j] = fmaf(a, w[j], h2[j]);
    }
    #pragma unroll
    for (int j = 0; j < 64; ++j) h2[j] = fmaxf(h2[j], 0.0f);

    // ---- node MLP layer 2: nm = relu(h2 @ Wn2 + bn2), Wn2 is [64][32]
    float nm[32];
    #pragma unroll
    for (int j = 0; j < 32; ++j) nm[j] = bn2[j];
    for (int k = 0; k < 64; ++k) {
        const float a = h2[k];
        const float* w = Wn2 + k * 32;
        #pragma unroll
        for (int j = 0; j < 32; ++j) nm[j] = fmaf(a, w[j], nm[j]);
    }

    // segment-sum into destination node (device-scope f32 atomics)
    float* out = nm_out + (size_t)d * 32;
    #pragma unroll
    for (int j = 0; j < 32; ++j) {
        atomicAdd(out + j, fmaxf(nm[j], 0.0f));
    }
}

extern "C" void kernel_launch(void* const* d_in, const int* in_sizes, int n_in,
                              void* d_out, int out_size, void* d_ws, size_t ws_size,
                              hipStream_t stream) {
    const float* x_node = (const float*)d_in[0];
    const float* x_edge = (const float*)d_in[1];
    const int*   src    = (const int*)d_in[2];
    const int*   dst    = (const int*)d_in[3];
    const float* We1 = (const float*)d_in[4];
    const float* be1 = (const float*)d_in[5];
    const float* We2 = (const float*)d_in[6];
    const float* be2 = (const float*)d_in[7];
    const float* Wn1 = (const float*)d_in[8];
    const float* bn1 = (const float*)d_in[9];
    const float* Wn2 = (const float*)d_in[10];
    const float* bn2 = (const float*)d_in[11];

    float* nm_out = (float*)d_out;                       // [N_NODES*32]
    float* em_out = (float*)d_out + (size_t)N_NODES * 32; // [N_EDGES*6]

    // d_out is poisoned to 0xAA before every timed launch -> zero the
    // atomic-accumulated region. edge_msg region is fully overwritten.
    hipMemsetAsync(nm_out, 0, (size_t)N_NODES * 32 * sizeof(float), stream);

    mpn_kernel<<<N_EDGES / 256, 256, 0, stream>>>(
        x_node, x_edge, src, dst,
        We1, be1, We2, be2, Wn1, bn1, Wn2, bn2,
        nm_out, em_out);
}

// Round 2
// 886.414 us; speedup vs baseline: 6.2021x; 6.2021x over previous
//
#include <hip/hip_runtime.h>

#define N_EDGES 3200000
#define N_NODES 100000

__global__ void __launch_bounds__(256) mpn_kernel(
    const float* __restrict__ x_node,
    const float* __restrict__ x_edge,
    const int* __restrict__ src,
    const int* __restrict__ dst,
    const float* __restrict__ We1, const float* __restrict__ be1,
    const float* __restrict__ We2, const float* __restrict__ be2,
    const float* __restrict__ Wn1, const float* __restrict__ bn1,
    const float* __restrict__ Wn2, const float* __restrict__ bn2,
    float* __restrict__ nm_out,   // [N_NODES, 32]
    float* __restrict__ em_out)   // [N_EDGES, 6]
{
    // Staging for coalesced segment-sum atomics. Stride 33 (+1 pad) makes both
    // the per-thread row write and the lane-major read <=2-way bank aliased
    // (free on gfx950).
    __shared__ float s_nm[256][33];
    __shared__ int   s_dst[256];

    const int tid = threadIdx.x;
    const int e = blockIdx.x * 256 + tid;
    const int d = dst[e];
    const int s = src[e];

    // Gather endpoint node features (128B rows, float4 loads; L2/L3 resident)
    float xd[32], xs[32];
    {
        const float4* pd = (const float4*)(x_node + (size_t)d * 32);
        const float4* ps = (const float4*)(x_node + (size_t)s * 32);
        #pragma unroll
        for (int i = 0; i < 8; ++i) {
            float4 v = pd[i];
            xd[4*i+0] = v.x; xd[4*i+1] = v.y; xd[4*i+2] = v.z; xd[4*i+3] = v.w;
        }
        #pragma unroll
        for (int i = 0; i < 8; ++i) {
            float4 v = ps[i];
            xs[4*i+0] = v.x; xs[4*i+1] = v.y; xs[4*i+2] = v.z; xs[4*i+3] = v.w;
        }
    }
    float xe[6];
    {
        const float2* pe = (const float2*)(x_edge + (size_t)e * 6);
        float2 a = pe[0], b = pe[1], c = pe[2];
        xe[0]=a.x; xe[1]=a.y; xe[2]=b.x; xe[3]=b.y; xe[4]=c.x; xe[5]=c.y;
    }

    // ---- edge MLP layer 1: h1 = relu([xd,xs,xe] @ We1 + be1), We1 is [70][32]
    float h1[32];
    #pragma unroll
    for (int j = 0; j < 32; ++j) h1[j] = be1[j];
    for (int k = 0; k < 32; ++k) {
        const float a = xd[k];
        const float* w = We1 + k * 32;
        #pragma unroll
        for (int j = 0; j < 32; ++j) h1[j] = fmaf(a, w[j], h1[j]);
    }
    for (int k = 0; k < 32; ++k) {
        const float a = xs[k];
        const float* w = We1 + (32 + k) * 32;
        #pragma unroll
        for (int j = 0; j < 32; ++j) h1[j] = fmaf(a, w[j], h1[j]);
    }
    #pragma unroll
    for (int k = 0; k < 6; ++k) {
        const float a = xe[k];
        const float* w = We1 + (64 + k) * 32;
        #pragma unroll
        for (int j = 0; j < 32; ++j) h1[j] = fmaf(a, w[j], h1[j]);
    }
    #pragma unroll
    for (int j = 0; j < 32; ++j) h1[j] = fmaxf(h1[j], 0.0f);

    // ---- edge MLP layer 2: em = relu(h1 @ We2 + be2), We2 is [32][6]
    float em[6];
    #pragma unroll
    for (int j = 0; j < 6; ++j) em[j] = be2[j];
    for (int k = 0; k < 32; ++k) {
        const float a = h1[k];
        const float* w = We2 + k * 6;
        #pragma unroll
        for (int j = 0; j < 6; ++j) em[j] = fmaf(a, w[j], em[j]);
    }
    #pragma unroll
    for (int j = 0; j < 6; ++j) em[j] = fmaxf(em[j], 0.0f);

    // write edge_msg [E,6] (second output)
    {
        float2* eo = (float2*)(em_out + (size_t)e * 6);
        eo[0] = make_float2(em[0], em[1]);
        eo[1] = make_float2(em[2], em[3]);
        eo[2] = make_float2(em[4], em[5]);
    }

    // ---- node MLP layer 1: h2 = relu([xd, em] @ Wn1 + bn1), Wn1 is [38][64]
    float h2[64];
    #pragma unroll
    for (int j = 0; j < 64; ++j) h2[j] = bn1[j];
    for (int k = 0; k < 32; ++k) {
        const float a = xd[k];
        const float* w = Wn1 + k * 64;
        #pragma unroll
        for (int j = 0; j < 64; ++j) h2[j] = fmaf(a, w[j], h2[j]);
    }
    #pragma unroll
    for (int k = 0; k < 6; ++k) {
        const float a = em[k];
        const float* w = Wn1 + (32 + k) * 64;
        #pragma unroll
        for (int j = 0; j < 64; ++j) h2[j] = fmaf(a, w[j], h2[j]);
    }
    #pragma unroll
    for (int j = 0; j < 64; ++j) h2[j] = fmaxf(h2[j], 0.0f);

    // ---- node MLP layer 2: nm = relu(h2 @ Wn2 + bn2), Wn2 is [64][32]
    float nm[32];
    #pragma unroll
    for (int j = 0; j < 32; ++j) nm[j] = bn2[j];
    for (int k = 0; k < 64; ++k) {
        const float a = h2[k];
        const float* w = Wn2 + k * 32;
        #pragma unroll
        for (int j = 0; j < 32; ++j) nm[j] = fmaf(a, w[j], nm[j]);
    }

    // ---- stage relu(nm) + dst in LDS, then block-coalesced atomics:
    // lane-major over features so one wave instruction covers 2 contiguous
    // 128B destination rows instead of 64 scattered lines.
    s_dst[tid] = d;
    #pragma unroll
    for (int j = 0; j < 32; ++j) s_nm[tid][j] = fmaxf(nm[j], 0.0f);
    __syncthreads();

    #pragma unroll 4
    for (int it = 0; it < 32; ++it) {
        const int f  = it * 256 + tid;   // flat index over 256 edges x 32 feats
        const int le = f >> 5;           // local edge
        const int j  = f & 31;           // feature
        const float v = s_nm[le][j];
        const int  dd = s_dst[le];
        atomicAdd(nm_out + (size_t)dd * 32 + j, v);
    }
}

extern "C" void kernel_launch(void* const* d_in, const int* in_sizes, int n_in,
                              void* d_out, int out_size, void* d_ws, size_t ws_size,
                              hipStream_t stream) {
    const float* x_node = (const float*)d_in[0];
    const float* x_edge = (const float*)d_in[1];
    const int*   src    = (const int*)d_in[2];
    const int*   dst    = (const int*)d_in[3];
    const float* We1 = (const float*)d_in[4];
    const float* be1 = (const float*)d_in[5];
    const float* We2 = (const float*)d_in[6];
    const float* be2 = (const float*)d_in[7];
    const float* Wn1 = (const float*)d_in[8];
    const float* bn1 = (const float*)d_in[9];
    const float* Wn2 = (const float*)d_in[10];
    const float* bn2 = (const float*)d_in[11];

    float* nm_out = (float*)d_out;                        // [N_NODES*32]
    float* em_out = (float*)d_out + (size_t)N_NODES * 32; // [N_EDGES*6]

    // d_out is poisoned to 0xAA before every timed launch -> zero the
    // atomic-accumulated region. edge_msg region is fully overwritten.
    hipMemsetAsync(nm_out, 0, (size_t)N_NODES * 32 * sizeof(float), stream);

    mpn_kernel<<<N_EDGES / 256, 256, 0, stream>>>(
        x_node, x_edge, src, dst,
        We1, be1, We2, be2, Wn1, bn1, Wn2, bn2,
        nm_out, em_out);
}

// Round 3
// 585.842 us; speedup vs baseline: 9.3842x; 1.5131x over previous
//
#include <hip/hip_runtime.h>

#define N_EDGES 3200000
#define N_NODES 100000

// ---------- bf16 helpers ----------
__device__ inline unsigned short f2bf(float f) {
    unsigned u = __float_as_uint(f);
    u += 0x7fffu + ((u >> 16) & 1u);       // round-to-nearest-even
    return (unsigned short)(u >> 16);
}
__device__ inline unsigned pack_bf2(float lo, float hi) {
    return (unsigned)f2bf(lo) | ((unsigned)f2bf(hi) << 16);
}
__device__ inline float bflo(unsigned u) { return __uint_as_float(u << 16); }
__device__ inline float bfhi(unsigned u) { return __uint_as_float(u & 0xffff0000u); }

// ---------- pass 1: per-node projections (nodes reused ~32x by edges) ----------
// Pd[n] = [ x@We1[0:32] + be1  (32) | x@Wn1[0:32] + bn1  (64) ]  -> 48 packed uints
// Ps[n] = [ x@We1[32:64]       (32) ]                            -> 16 packed uints
__global__ void __launch_bounds__(256) mpn_precompute(
    const float* __restrict__ x_node,
    const float* __restrict__ We1, const float* __restrict__ be1,
    const float* __restrict__ Wn1, const float* __restrict__ bn1,
    unsigned* __restrict__ Pd, unsigned* __restrict__ Ps)
{
    const int n = blockIdx.x * 256 + threadIdx.x;
    if (n >= N_NODES) return;

    float x[32];
    {
        const float4* px = (const float4*)(x_node + (size_t)n * 32);
        #pragma unroll
        for (int i = 0; i < 8; ++i) {
            float4 v = px[i];
            x[4*i+0] = v.x; x[4*i+1] = v.y; x[4*i+2] = v.z; x[4*i+3] = v.w;
        }
    }

    float p1[32];
    #pragma unroll
    for (int j = 0; j < 32; ++j) p1[j] = be1[j];
    for (int k = 0; k < 32; ++k) {
        const float a = x[k];
        const float* w = We1 + k * 32;
        #pragma unroll
        for (int j = 0; j < 32; ++j) p1[j] = fmaf(a, w[j], p1[j]);
    }
    unsigned* pd = Pd + (size_t)n * 48;
    #pragma unroll
    for (int i = 0; i < 16; ++i) pd[i] = pack_bf2(p1[2*i], p1[2*i+1]);

    float p3[64];
    #pragma unroll
    for (int j = 0; j < 64; ++j) p3[j] = bn1[j];
    for (int k = 0; k < 32; ++k) {
        const float a = x[k];
        const float* w = Wn1 + k * 64;
        #pragma unroll
        for (int j = 0; j < 64; ++j) p3[j] = fmaf(a, w[j], p3[j]);
    }
    #pragma unroll
    for (int i = 0; i < 32; ++i) pd[16 + i] = pack_bf2(p3[2*i], p3[2*i+1]);

    float p2[32];
    #pragma unroll
    for (int j = 0; j < 32; ++j) p2[j] = 0.0f;
    for (int k = 0; k < 32; ++k) {
        const float a = x[k];
        const float* w = We1 + (32 + k) * 32;
        #pragma unroll
        for (int j = 0; j < 32; ++j) p2[j] = fmaf(a, w[j], p2[j]);
    }
    unsigned* ps = Ps + (size_t)n * 16;
    #pragma unroll
    for (int i = 0; i < 16; ++i) ps[i] = pack_bf2(p2[2*i], p2[2*i+1]);
}

// ---------- pass 2: per-edge fused MLPs + coalesced atomic segment-sum ----------
__global__ void __launch_bounds__(256) mpn_main(
    const unsigned* __restrict__ Pd,
    const unsigned* __restrict__ Ps,
    const float* __restrict__ x_edge,
    const int* __restrict__ src,
    const int* __restrict__ dst,
    const float* __restrict__ We1,  // only rows 64..69 used
    const float* __restrict__ We2, const float* __restrict__ be2,
    const float* __restrict__ Wn1,  // only rows 32..37 used
    const float* __restrict__ Wn2, const float* __restrict__ bn2,
    float* __restrict__ nm_out,   // [N_NODES, 32]
    float* __restrict__ em_out)   // [N_EDGES, 6]
{
    // chunked staging (128 edges at a time) keeps LDS at ~17.4 KB
    __shared__ float s_nm[128][33];
    __shared__ int   s_dst[128];

    const int tid = threadIdx.x;
    const int e = blockIdx.x * 256 + tid;
    const int d = dst[e];
    const int s = src[e];

    const uint4* pdrow = (const uint4*)(Pd + (size_t)d * 48);
    const uint4* psrow = (const uint4*)(Ps + (size_t)s * 16);

    // ---- edge MLP layer 1: h1 = relu(P1[d] + P2[s] + xe @ We1[64:70])
    float h1[32];
    #pragma unroll
    for (int i = 0; i < 4; ++i) {
        uint4 va = pdrow[i];
        uint4 vb = psrow[i];
        h1[8*i+0] = bflo(va.x) + bflo(vb.x);
        h1[8*i+1] = bfhi(va.x) + bfhi(vb.x);
        h1[8*i+2] = bflo(va.y) + bflo(vb.y);
        h1[8*i+3] = bfhi(va.y) + bfhi(vb.y);
        h1[8*i+4] = bflo(va.z) + bflo(vb.z);
        h1[8*i+5] = bfhi(va.z) + bfhi(vb.z);
        h1[8*i+6] = bflo(va.w) + bflo(vb.w);
        h1[8*i+7] = bfhi(va.w) + bfhi(vb.w);
    }
    float xe[6];
    {
        const float2* pe = (const float2*)(x_edge + (size_t)e * 6);
        float2 a = pe[0], b = pe[1], c = pe[2];
        xe[0]=a.x; xe[1]=a.y; xe[2]=b.x; xe[3]=b.y; xe[4]=c.x; xe[5]=c.y;
    }
    #pragma unroll
    for (int k = 0; k < 6; ++k) {
        const float a = xe[k];
        const float* w = We1 + (64 + k) * 32;
        #pragma unroll
        for (int j = 0; j < 32; ++j) h1[j] = fmaf(a, w[j], h1[j]);
    }
    #pragma unroll
    for (int j = 0; j < 32; ++j) h1[j] = fmaxf(h1[j], 0.0f);

    // ---- edge MLP layer 2: em = relu(h1 @ We2 + be2)
    float em[6];
    #pragma unroll
    for (int j = 0; j < 6; ++j) em[j] = be2[j];
    for (int k = 0; k < 32; ++k) {
        const float a = h1[k];
        const float* w = We2 + k * 6;
        #pragma unroll
        for (int j = 0; j < 6; ++j) em[j] = fmaf(a, w[j], em[j]);
    }
    #pragma unroll
    for (int j = 0; j < 6; ++j) em[j] = fmaxf(em[j], 0.0f);

    {
        float2* eo = (float2*)(em_out + (size_t)e * 6);
        eo[0] = make_float2(em[0], em[1]);
        eo[1] = make_float2(em[2], em[3]);
        eo[2] = make_float2(em[4], em[5]);
    }

    // ---- node MLP layer 1: h2 = relu(P3[d] + em @ Wn1[32:38])
    float h2[64];
    #pragma unroll
    for (int i = 0; i < 8; ++i) {
        uint4 v = pdrow[4 + i];
        h2[8*i+0] = bflo(v.x); h2[8*i+1] = bfhi(v.x);
        h2[8*i+2] = bflo(v.y); h2[8*i+3] = bfhi(v.y);
        h2[8*i+4] = bflo(v.z); h2[8*i+5] = bfhi(v.z);
        h2[8*i+6] = bflo(v.w); h2[8*i+7] = bfhi(v.w);
    }
    #pragma unroll
    for (int k = 0; k < 6; ++k) {
        const float a = em[k];
        const float* w = Wn1 + (32 + k) * 64;
        #pragma unroll
        for (int j = 0; j < 64; ++j) h2[j] = fmaf(a, w[j], h2[j]);
    }
    #pragma unroll
    for (int j = 0; j < 64; ++j) h2[j] = fmaxf(h2[j], 0.0f);

    // ---- node MLP layer 2: nm = relu(h2 @ Wn2 + bn2)
    float nm[32];
    #pragma unroll
    for (int j = 0; j < 32; ++j) nm[j] = bn2[j];
    for (int k = 0; k < 64; ++k) {
        const float a = h2[k];
        const float* w = Wn2 + k * 32;
        #pragma unroll
        for (int j = 0; j < 32; ++j) nm[j] = fmaf(a, w[j], nm[j]);
    }

    // ---- coalesced atomic segment-sum, 2 chunks of 128 edges
    #pragma unroll
    for (int chunk = 0; chunk < 2; ++chunk) {
        __syncthreads();
        if ((tid >> 7) == chunk) {
            const int lt = tid & 127;
            s_dst[lt] = d;
            #pragma unroll
            for (int j = 0; j < 32; ++j) s_nm[lt][j] = fmaxf(nm[j], 0.0f);
        }
        __syncthreads();
        #pragma unroll 4
        for (int it = 0; it < 16; ++it) {
            const int f  = it * 256 + tid;   // 128 edges x 32 feats
            const int le = f >> 5;
            const int j  = f & 31;
            atomicAdd(nm_out + (size_t)s_dst[le] * 32 + j, s_nm[le][j]);
        }
    }
}

extern "C" void kernel_launch(void* const* d_in, const int* in_sizes, int n_in,
                              void* d_out, int out_size, void* d_ws, size_t ws_size,
                              hipStream_t stream) {
    const float* x_node = (const float*)d_in[0];
    const float* x_edge = (const float*)d_in[1];
    const int*   src    = (const int*)d_in[2];
    const int*   dst    = (const int*)d_in[3];
    const float* We1 = (const float*)d_in[4];
    const float* be1 = (const float*)d_in[5];
    const float* We2 = (const float*)d_in[6];
    const float* be2 = (const float*)d_in[7];
    const float* Wn1 = (const float*)d_in[8];
    const float* bn1 = (const float*)d_in[9];
    const float* Wn2 = (const float*)d_in[10];
    const float* bn2 = (const float*)d_in[11];

    float* nm_out = (float*)d_out;                        // [N_NODES*32]
    float* em_out = (float*)d_out + (size_t)N_NODES * 32; // [N_EDGES*6]

    // workspace: bf16 per-node projection tables (25.6 MB)
    unsigned* Pd = (unsigned*)d_ws;                 // [N_NODES][48] packed bf16x2
    unsigned* Ps = Pd + (size_t)N_NODES * 48;       // [N_NODES][16]

    hipMemsetAsync(nm_out, 0, (size_t)N_NODES * 32 * sizeof(float), stream);

    mpn_precompute<<<(N_NODES + 255) / 256, 256, 0, stream>>>(
        x_node, We1, be1, Wn1, bn1, Pd, Ps);

    mpn_main<<<N_EDGES / 256, 256, 0, stream>>>(
        Pd, Ps, x_edge, src, dst,
        We1, We2, be2, Wn1, Wn2, bn2,
        nm_out, em_out);
}

// Round 4
// 534.020 us; speedup vs baseline: 10.2948x; 1.0970x over previous
//
#include <hip/hip_runtime.h>

#define N_EDGES 3200000
#define N_NODES 100000

typedef __attribute__((ext_vector_type(8))) short bf16x8;  // 8 bf16 in 4 VGPRs
typedef __attribute__((ext_vector_type(4))) float f32x4;

// ---------- bf16 helpers ----------
__device__ inline unsigned short f2bf(float f) {
    unsigned u = __float_as_uint(f);
    u += 0x7fffu + ((u >> 16) & 1u);       // round-to-nearest-even
    return (unsigned short)(u >> 16);
}
__device__ inline unsigned pack_bf2(float lo, float hi) {
    return (unsigned)f2bf(lo) | ((unsigned)f2bf(hi) << 16);
}
__device__ inline float bflo(unsigned u) { return __uint_as_float(u << 16); }
__device__ inline float bfhi(unsigned u) { return __uint_as_float(u & 0xffff0000u); }

// ---------- pass 1: per-node projections + output zeroing + Wn2^T ----------
// Pd[n] = [ x@We1[0:32] + be1  (32) | x@Wn1[0:32] + bn1  (64) ]  -> 48 packed uints
// Ps[n] = [ x@We1[32:64]       (32) ]                            -> 16 packed uints
__global__ void __launch_bounds__(256) mpn_precompute(
    const float* __restrict__ x_node,
    const float* __restrict__ We1, const float* __restrict__ be1,
    const float* __restrict__ Wn1, const float* __restrict__ bn1,
    const float* __restrict__ Wn2,
    unsigned* __restrict__ Pd, unsigned* __restrict__ Ps,
    short* __restrict__ Wn2T,            // [32][64] bf16
    float* __restrict__ nm_out)          // zeroed here (poisoned by harness)
{
    const int n = blockIdx.x * 256 + threadIdx.x;
    if (n >= N_NODES) return;

    // zero the atomic-accumulated output region
    {
        float4 z = make_float4(0.f, 0.f, 0.f, 0.f);
        float4* o = (float4*)(nm_out + (size_t)n * 32);
        #pragma unroll
        for (int i = 0; i < 8; ++i) o[i] = z;
    }
    // transpose Wn2 [64][32] -> Wn2T [32][64] bf16 (first 2048 threads)
    if (n < 2048) Wn2T[n] = (short)f2bf(Wn2[(n & 63) * 32 + (n >> 6)]);

    float x[32];
    {
        const float4* px = (const float4*)(x_node + (size_t)n * 32);
        #pragma unroll
        for (int i = 0; i < 8; ++i) {
            float4 v = px[i];
            x[4*i+0] = v.x; x[4*i+1] = v.y; x[4*i+2] = v.z; x[4*i+3] = v.w;
        }
    }

    float p1[32];
    #pragma unroll
    for (int j = 0; j < 32; ++j) p1[j] = be1[j];
    for (int k = 0; k < 32; ++k) {
        const float a = x[k];
        const float* w = We1 + k * 32;
        #pragma unroll
        for (int j = 0; j < 32; ++j) p1[j] = fmaf(a, w[j], p1[j]);
    }
    unsigned* pd = Pd + (size_t)n * 48;
    #pragma unroll
    for (int i = 0; i < 16; ++i) pd[i] = pack_bf2(p1[2*i], p1[2*i+1]);

    float p3[64];
    #pragma unroll
    for (int j = 0; j < 64; ++j) p3[j] = bn1[j];
    for (int k = 0; k < 32; ++k) {
        const float a = x[k];
        const float* w = Wn1 + k * 64;
        #pragma unroll
        for (int j = 0; j < 64; ++j) p3[j] = fmaf(a, w[j], p3[j]);
    }
    #pragma unroll
    for (int i = 0; i < 32; ++i) pd[16 + i] = pack_bf2(p3[2*i], p3[2*i+1]);

    float p2[32];
    #pragma unroll
    for (int j = 0; j < 32; ++j) p2[j] = 0.0f;
    for (int k = 0; k < 32; ++k) {
        const float a = x[k];
        const float* w = We1 + (32 + k) * 32;
        #pragma unroll
        for (int j = 0; j < 32; ++j) p2[j] = fmaf(a, w[j], p2[j]);
    }
    unsigned* ps = Ps + (size_t)n * 16;
    #pragma unroll
    for (int i = 0; i < 16; ++i) ps[i] = pack_bf2(p2[2*i], p2[2*i+1]);
}

// ---------- pass 2: per-edge MLPs (h2@Wn2 via MFMA) + coalesced atomics ----------
__global__ void __launch_bounds__(256) mpn_main(
    const unsigned* __restrict__ Pd,
    const unsigned* __restrict__ Ps,
    const float* __restrict__ x_edge,
    const int* __restrict__ src,
    const int* __restrict__ dst,
    const float* __restrict__ We1,  // rows 64..69
    const float* __restrict__ We2, const float* __restrict__ be2,
    const float* __restrict__ Wn1,  // rows 32..37
    const short* __restrict__ Wn2T, // [32][64] bf16
    const float* __restrict__ bn2,
    float* __restrict__ nm_out,   // [N_NODES, 32]
    float* __restrict__ em_out)   // [N_EDGES, 6]
{
    // Per-wave h2 tiles: 4 waves x 64 rows x 72 bf16 (stride 144 B: 16B-aligned
    // b128 ops, bank-balanced). Reused afterwards as s_nm[128][33] f32 staging.
    __shared__ unsigned s_h2[4][64][36];   // 36864 B
    __shared__ int      s_dst[128];

    const int tid  = threadIdx.x;
    const int lane = tid & 63;
    const int wave = tid >> 6;
    const int quad = lane >> 4;
    const int l15  = lane & 15;

    const int e = blockIdx.x * 256 + tid;
    const int d = dst[e];
    const int s = src[e];

    const uint4* pdrow = (const uint4*)(Pd + (size_t)d * 48);
    const uint4* psrow = (const uint4*)(Ps + (size_t)s * 16);

    // ---- edge MLP layer 1: h1 = relu(P1[d] + P2[s] + xe @ We1[64:70])
    float h1[32];
    #pragma unroll
    for (int i = 0; i < 4; ++i) {
        uint4 va = pdrow[i];
        uint4 vb = psrow[i];
        h1[8*i+0] = bflo(va.x) + bflo(vb.x);
        h1[8*i+1] = bfhi(va.x) + bfhi(vb.x);
        h1[8*i+2] = bflo(va.y) + bflo(vb.y);
        h1[8*i+3] = bfhi(va.y) + bfhi(vb.y);
        h1[8*i+4] = bflo(va.z) + bflo(vb.z);
        h1[8*i+5] = bfhi(va.z) + bfhi(vb.z);
        h1[8*i+6] = bflo(va.w) + bflo(vb.w);
        h1[8*i+7] = bfhi(va.w) + bfhi(vb.w);
    }
    float xe[6];
    {
        const float2* pe = (const float2*)(x_edge + (size_t)e * 6);
        float2 a = pe[0], b = pe[1], c = pe[2];
        xe[0]=a.x; xe[1]=a.y; xe[2]=b.x; xe[3]=b.y; xe[4]=c.x; xe[5]=c.y;
    }
    #pragma unroll
    for (int k = 0; k < 6; ++k) {
        const float a = xe[k];
        const float* w = We1 + (64 + k) * 32;
        #pragma unroll
        for (int j = 0; j < 32; ++j) h1[j] = fmaf(a, w[j], h1[j]);
    }
    #pragma unroll
    for (int j = 0; j < 32; ++j) h1[j] = fmaxf(h1[j], 0.0f);

    // ---- edge MLP layer 2: em = relu(h1 @ We2 + be2)
    float em[6];
    #pragma unroll
    for (int j = 0; j < 6; ++j) em[j] = be2[j];
    for (int k = 0; k < 32; ++k) {
        const float a = h1[k];
        const float* w = We2 + k * 6;
        #pragma unroll
        for (int j = 0; j < 6; ++j) em[j] = fmaf(a, w[j], em[j]);
    }
    #pragma unroll
    for (int j = 0; j < 6; ++j) em[j] = fmaxf(em[j], 0.0f);

    {
        float2* eo = (float2*)(em_out + (size_t)e * 6);
        eo[0] = make_float2(em[0], em[1]);
        eo[1] = make_float2(em[2], em[3]);
        eo[2] = make_float2(em[4], em[5]);
    }

    // ---- node MLP layer 1: h2 = relu(P3[d] + em @ Wn1[32:38])
    float h2[64];
    #pragma unroll
    for (int i = 0; i < 8; ++i) {
        uint4 v = pdrow[4 + i];
        h2[8*i+0] = bflo(v.x); h2[8*i+1] = bfhi(v.x);
        h2[8*i+2] = bflo(v.y); h2[8*i+3] = bfhi(v.y);
        h2[8*i+4] = bflo(v.z); h2[8*i+5] = bfhi(v.z);
        h2[8*i+6] = bflo(v.w); h2[8*i+7] = bfhi(v.w);
    }
    #pragma unroll
    for (int k = 0; k < 6; ++k) {
        const float a = em[k];
        const float* w = Wn1 + (32 + k) * 64;
        #pragma unroll
        for (int j = 0; j < 64; ++j) h2[j] = fmaf(a, w[j], h2[j]);
    }

    // pack relu(h2) -> bf16, stage in this wave's LDS tile (row = lane)
    {
        uint4* row = (uint4*)&s_h2[wave][lane][0];
        #pragma unroll
        for (int i = 0; i < 8; ++i) {
            uint4 v;
            v.x = pack_bf2(fmaxf(h2[8*i+0],0.f), fmaxf(h2[8*i+1],0.f));
            v.y = pack_bf2(fmaxf(h2[8*i+2],0.f), fmaxf(h2[8*i+3],0.f));
            v.z = pack_bf2(fmaxf(h2[8*i+4],0.f), fmaxf(h2[8*i+5],0.f));
            v.w = pack_bf2(fmaxf(h2[8*i+6],0.f), fmaxf(h2[8*i+7],0.f));
            row[i] = v;
        }
    }
    __syncthreads();   // also orders LDS writes vs fragment reads

    // ---- nm = h2 @ Wn2 via MFMA: M=64 edges, N=32 outs, K=64
    // B frags from Wn2T[n][k] (global, L1-resident): lane holds B[n=l15][k=quad*8+j]
    bf16x8 bfr[2][2];
    #pragma unroll
    for (int n = 0; n < 2; ++n)
        #pragma unroll
        for (int kt = 0; kt < 2; ++kt)
            bfr[n][kt] = *(const bf16x8*)(Wn2T + (n*16 + l15)*64 + kt*32 + quad*8);

    f32x4 acc[4][2];
    #pragma unroll
    for (int m = 0; m < 4; ++m) { acc[m][0] = (f32x4)0.f; acc[m][1] = (f32x4)0.f; }

    #pragma unroll
    for (int m = 0; m < 4; ++m) {
        #pragma unroll
        for (int kt = 0; kt < 2; ++kt) {
            // A[m'=l15][k=quad*8+j] from edge row m*16+l15 of this wave's tile
            bf16x8 af = *(const bf16x8*)((const char*)&s_h2[wave][m*16 + l15][0]
                                         + kt*64 + quad*16);
            acc[m][0] = __builtin_amdgcn_mfma_f32_16x16x32_bf16(af, bfr[0][kt], acc[m][0], 0, 0, 0);
            acc[m][1] = __builtin_amdgcn_mfma_f32_16x16x32_bf16(af, bfr[1][kt], acc[m][1], 0, 0, 0);
        }
    }

    const float b0 = bn2[l15];
    const float b1 = bn2[16 + l15];

    // ---- coalesced atomic segment-sum, 2 chunks of 128 edges
    // (LDS tile reused as s_nm[128][33] f32)
    float* s_nm = (float*)s_h2;
    #pragma unroll
    for (int chunk = 0; chunk < 2; ++chunk) {
        __syncthreads();
        if ((tid >> 7) == chunk) {
            s_dst[tid & 127] = d;                        // own edge's dst
            const int be = (wave & 1) * 64;              // C-layout scatter
            #pragma unroll
            for (int m = 0; m < 4; ++m) {
                #pragma unroll
                for (int n = 0; n < 2; ++n) {
                    const float bb = n ? b1 : b0;
                    #pragma unroll
                    for (int r = 0; r < 4; ++r) {
                        const int le  = be + m*16 + quad*4 + r;   // edge (row)
                        const int out = n*16 + l15;               // feature (col)
                        s_nm[le*33 + out] = fmaxf(acc[m][n][r] + bb, 0.0f);
                    }
                }
            }
        }
        __syncthreads();
        #pragma unroll 4
        for (int it = 0; it < 16; ++it) {
            const int f  = it * 256 + tid;   // 128 edges x 32 feats
            const int le = f >> 5;
            const int j  = f & 31;
            atomicAdd(nm_out + (size_t)s_dst[le] * 32 + j, s_nm[le*33 + j]);
        }
    }
}

extern "C" void kernel_launch(void* const* d_in, const int* in_sizes, int n_in,
                              void* d_out, int out_size, void* d_ws, size_t ws_size,
                              hipStream_t stream) {
    const float* x_node = (const float*)d_in[0];
    const float* x_edge = (const float*)d_in[1];
    const int*   src    = (const int*)d_in[2];
    const int*   dst    = (const int*)d_in[3];
    const float* We1 = (const float*)d_in[4];
    const float* be1 = (const float*)d_in[5];
    const float* We2 = (const float*)d_in[6];
    const float* be2 = (const float*)d_in[7];
    const float* Wn1 = (const float*)d_in[8];
    const float* bn1 = (const float*)d_in[9];
    const float* Wn2 = (const float*)d_in[10];
    const float* bn2 = (const float*)d_in[11];

    float* nm_out = (float*)d_out;                        // [N_NODES*32]
    float* em_out = (float*)d_out + (size_t)N_NODES * 32; // [N_EDGES*6]

    // workspace: bf16 per-node projection tables (25.6 MB) + Wn2^T (4 KB)
    unsigned* Pd   = (unsigned*)d_ws;               // [N_NODES][48] packed bf16x2
    unsigned* Ps   = Pd + (size_t)N_NODES * 48;     // [N_NODES][16]
    short*    Wn2T = (short*)(Ps + (size_t)N_NODES * 16);  // [32][64] bf16

    mpn_precompute<<<(N_NODES + 255) / 256, 256, 0, stream>>>(
        x_node, We1, be1, Wn1, bn1, Wn2, Pd, Ps, Wn2T, nm_out);

    mpn_main<<<N_EDGES / 256, 256, 0, stream>>>(
        Pd, Ps, x_edge, src, dst,
        We1, We2, be2, Wn1, Wn2T, bn2,
        nm_out, em_out);
}